// Round 1
// 276.413 us; speedup vs baseline: 1.0463x; 1.0463x over previous
//
#include <hip/hip_runtime.h>
#include <hip/hip_bf16.h>

// N=4096, K=48, P=128, A=5, NBINS=16, RP=32
#define N_RES 4096
#define KNB   48
#define PCH   128
#define INV_STEP 0.727272727272727f
#define E2INV 0.13533528323661270f   // e^-2

typedef __bf16 bf16x8 __attribute__((ext_vector_type(8)));
typedef float  f32x4  __attribute__((ext_vector_type(4)));

// Frag-linear, PADDED layout: octet stride = 49 row-slots (16B each) so the
// 784B oct stride lands on bank offset 4 -> b128 loads / b32 stores <=2-way.
#define FOCT(o,m) (((o)*49 + (m))*8)

// wcat: K=480 (0..15 dmap | 16..415 dist | 416..430 dir | 431..445 vec |
//       446..454 rot | 455..479 zero), layout [oct 60][col 128][8]
__device__ __align__(16) unsigned short g_wcat[60*128*8];
// w1: K=128 (rows sigma-permuted: pairs (u,u+16) interleaved), 256 cols
__device__ __align__(16) unsigned short g_w1[16*256*8];
// w2: K=256 (rows sigma-permuted within each 128-half), 128 cols
__device__ __align__(16) unsigned short g_w2[32*128*8];

__device__ __forceinline__ unsigned short f2bf(float f) {
  unsigned int u = __float_as_uint(f);
  return (unsigned short)((u + 0x7fffu + ((u >> 16) & 1u)) >> 16);
}
__device__ __forceinline__ unsigned int pk2(float a, float b) {
  __hip_bfloat162 h = __float22bfloat162_rn(make_float2(a, b));
  unsigned int u; __builtin_memcpy(&u, &h, 4); return u;
}
// tanh-gelu == x * sigmoid(2u), u = 0.7978845608*(x + 0.044715 x^3).
// Branch-free, rcp instead of precise divide: ~8 VALU ops.
__device__ __forceinline__ float gelu_f(float x) {
  float p = x * x;
  float q = fmaf(p, 0.044715f, 1.0f);
  float r = x * q;
  float e = __expf(-1.5957691216057308f * r);
  return x * __builtin_amdgcn_rcpf(1.0f + e);
}
__device__ __forceinline__ void frame_from_pos(const float* p, float* R) {
  float cax = p[3], cay = p[4], caz = p[5];
  float e1x = p[6]-cax, e1y = p[7]-cay, e1z = p[8]-caz;
  float i1 = __builtin_amdgcn_rsqf(fmaxf(e1x*e1x + e1y*e1y + e1z*e1z, 1e-6f));
  e1x *= i1; e1y *= i1; e1z *= i1;
  float vx = p[0]-cax, vy = p[1]-cay, vz = p[2]-caz;
  float dp = vx*e1x + vy*e1y + vz*e1z;
  float e2x = vx - dp*e1x, e2y = vy - dp*e1y, e2z = vz - dp*e1z;
  float i2 = __builtin_amdgcn_rsqf(fmaxf(e2x*e2x + e2y*e2y + e2z*e2z, 1e-6f));
  e2x *= i2; e2y *= i2; e2z *= i2;
  float e3x = e1y*e2z - e1z*e2y;
  float e3y = e1z*e2x - e1x*e2z;
  float e3z = e1x*e2y - e1y*e2x;
  R[0]=e1x; R[1]=e2x; R[2]=e3x;
  R[3]=e1y; R[4]=e2y; R[5]=e3y;
  R[6]=e1z; R[7]=e2z; R[8]=e3z;
}

// 16 RBF bins exp(-(x-b)^2) via two telescoping recurrences (up + down, merged
// with max to dodge underflow); two 16B frag-linear (padded) LDS stores.
__device__ __forceinline__ void stage_bins(unsigned short* sF, const float* s_xall,
                                           int xbase, int ntasks, int t) {
  for (int i = t; i < ntasks; i += 256) {
    int rloc = i / 48;
    int m = i - 48*rloc;
    float x = fminf(s_xall[(xbase + rloc)*48 + m], 25.0f);
    float u  = __expf(-x*x);
    float wu = __expf(2.0f*x - 1.0f);
    float xm = x - 15.0f;
    float d  = __expf(-xm*xm);
    float wd = __expf(-2.0f*xm - 1.0f);
    float bins[16];
    bins[0] = u;
    #pragma unroll
    for (int b = 1; b < 16; ++b) { u *= wu; wu *= E2INV; bins[b] = u; }
    bins[15] = fmaxf(bins[15], d);
    #pragma unroll
    for (int b = 14; b >= 0; --b) { d *= wd; wd *= E2INV; bins[b] = fmaxf(bins[b], d); }
    unsigned int p0 = pk2(bins[0], bins[1]),  p1 = pk2(bins[2], bins[3]);
    unsigned int p2 = pk2(bins[4], bins[5]),  p3 = pk2(bins[6], bins[7]);
    unsigned int p4 = pk2(bins[8], bins[9]),  p5 = pk2(bins[10], bins[11]);
    unsigned int p6 = pk2(bins[12], bins[13]),p7 = pk2(bins[14], bins[15]);
    int base = FOCT(2*rloc, m);
    *(uint4*)(sF + base)       = make_uint4(p0,p1,p2,p3);
    *(uint4*)(sF + base + 392) = make_uint4(p4,p5,p6,p7);   // oct+1 => +49*8
  }
}

// ---- prep: fragment-linear bf16 weights; W1 rows / W2 rows sigma-permuted
// to match the paired (pk2/b32) LDS staging of their K operands. ----
__global__ __launch_bounds__(256) void prep_weights(
    const float* __restrict__ W_dmap, const float* __restrict__ W_dist,
    const float* __restrict__ W_dir, const float* __restrict__ W_rot,
    const float* __restrict__ W_vec, const float* __restrict__ W1,
    const float* __restrict__ W2)
{
  int i = blockIdx.x*256 + threadIdx.x;
  unsigned short pk[8];
  if (i < 7680) {                       // wcat: oct = i>>7 (60), col = i&127
    int oct = i >> 7, col = i & 127;
    #pragma unroll
    for (int j = 0; j < 8; ++j) {
      int k = oct*8 + j;
      float v;
      if      (k < 16)  v = W_dmap[k*128 + col];
      else if (k < 416) v = W_dist[(k-16)*128 + col];
      else if (k < 431) v = W_dir[(k-416)*128 + col];
      else if (k < 446) v = W_vec[(k-431)*128 + col];
      else if (k < 455) v = W_rot[(k-446)*128 + col];
      else              v = 0.0f;
      pk[j] = f2bf(v);
    }
    *(uint4*)(g_wcat + i*8) = *(uint4*)pk;
  } else if (i < 11776) {               // w1: oct(16) x col(256), rows permuted
    int j2 = i - 7680;
    int oct = j2 >> 8, col = j2 & 255;
    #pragma unroll
    for (int j = 0; j < 8; ++j) {
      int k = oct*8 + j;                // permuted row index
      int h = 32*(k>>5) + (k&1)*16 + ((k&31)>>1);   // original row
      pk[j] = f2bf(W1[h*256 + col]);
    }
    *(uint4*)(g_w1 + j2*8) = *(uint4*)pk;
  } else if (i < 15872) {               // w2: oct(32) x col(128), rows permuted per half
    int j3 = i - 11776;
    int oct = j3 >> 7, col = j3 & 127;
    #pragma unroll
    for (int j = 0; j < 8; ++j) {
      int k = oct*8 + j;                // permuted row 0..255
      int kh = k & 127;
      int h = (k>>7)*128 + 32*(kh>>5) + (kh&1)*16 + ((kh&31)>>1);
      pk[j] = f2bf(W2[h*128 + col]);
    }
    *(uint4*)(g_w2 + j3*8) = *(uint4*)pk;
  }
}

#define MFMA6(A0,A1,A2,B0,B1,ACC) \
  ACC[0][0] = __builtin_amdgcn_mfma_f32_16x16x32_bf16(A0, B0, ACC[0][0], 0,0,0); \
  ACC[1][0] = __builtin_amdgcn_mfma_f32_16x16x32_bf16(A1, B0, ACC[1][0], 0,0,0); \
  ACC[2][0] = __builtin_amdgcn_mfma_f32_16x16x32_bf16(A2, B0, ACC[2][0], 0,0,0); \
  ACC[0][1] = __builtin_amdgcn_mfma_f32_16x16x32_bf16(A0, B1, ACC[0][1], 0,0,0); \
  ACC[1][1] = __builtin_amdgcn_mfma_f32_16x16x32_bf16(A1, B1, ACC[1][1], 0,0,0); \
  ACC[2][1] = __builtin_amdgcn_mfma_f32_16x16x32_bf16(A2, B1, ACC[2][1], 0,0,0);

// ---- main: one block per residue, 256 threads; LDS ~25.5 KB -> 6 blocks/CU ----
__global__ __launch_bounds__(256, 6) void fused_struct_kernel(
    const float* __restrict__ pos, const float* __restrict__ dmap,
    const float* __restrict__ mask, const float* __restrict__ W_relpos,
    const float* __restrict__ ln_scale, const float* __restrict__ ln_offset,
    const float* __restrict__ b1, const float* __restrict__ b2,
    const int* __restrict__ neighbours, const int* __restrict__ resi,
    const int* __restrict__ chain, const int* __restrict__ batch,
    float* __restrict__ out)
{
  const int n = blockIdx.x;
  const int t = threadIdx.x;
  const int lane = t & 63;
  const int wv   = t >> 6;
  const int ln15 = lane & 15;
  const int quad = lane >> 4;

  __shared__ __align__(16) char regF[12544];   // F stage / hb half (padded frag-linear)
  __shared__ __align__(16) char regP[12544];   // scratch -> pairb
  __shared__ __align__(16) float2 s_stats[48];

  unsigned short* sF    = (unsigned short*)regF;
  unsigned short* sPair = (unsigned short*)regP;
  float*  s_posnb = (float*)regP;              // [48][16]
  float*  s_Rnb   = (float*)(regP + 3072);     // [48][12]
  float*  s_xall  = (float*)(regP + 5376);     // [26][48]
  float*  s_posn  = (float*)(regP + 10368);    // 16
  float*  s_Rn    = (float*)(regP + 10432);    // 12
  int*    s_cls   = (int*)  (regP + 10496);    // 48
  float2* s_part  = (float2*)(regP + 10752);   // [4][48]

  // ---------------- P1 ----------------
  if (t < KNB) {
    const int k = t;
    const int nbraw = neighbours[n*KNB + k];
    int nb = nbraw; if (nb < 0) nb += N_RES;
    float p[15];
    const float* pp = pos + nb*15;
    #pragma unroll
    for (int d = 0; d < 15; ++d) { p[d] = pp[d]; s_posnb[k*16+d] = p[d]; }
    float R[9];
    frame_from_pos(p, R);
    #pragma unroll
    for (int d = 0; d < 9; ++d) s_Rnb[k*12+d] = R[d];

    float pm = mask[n] * mask[nb] * ((nbraw != -1) ? 1.0f : 0.0f);
    out[N_RES*KNB*PCH + n*KNB + k] = pm;

    int rel = resi[nb] - resi[n];
    rel = (rel < -32) ? -32 : (rel > 32 ? 32 : rel);
    rel += 32;
    bool same = (chain[nb] == chain[n]) && (batch[nb] == batch[n]);
    s_cls[k] = same ? rel : 65;

    float xd = dmap[(long long)n*N_RES + nb] * INV_STEP;
    s_xall[k] = (pm > 0.0f) ? xd : 30.0f;     // 30 -> all bins underflow to 0
  } else if (t == 255) {
    float p[15];
    const float* pp = pos + n*15;
    #pragma unroll
    for (int d = 0; d < 15; ++d) { p[d] = pp[d]; s_posn[d] = p[d]; }
    float R[9];
    frame_from_pos(p, R);
    #pragma unroll
    for (int d = 0; d < 9; ++d) s_Rn[d] = R[d];
  }
  __syncthreads();

  // ---------------- P2: 25 atom-pair scaled distances ----------------
  for (int idx = t; idx < 1200; idx += 256) {
    int c = idx / 48, k = idx - 48*c;
    int a1 = c / 5, a2 = c - 5*a1;
    float dx = s_posn[a1*3+0] - s_posnb[k*16 + a2*3+0];
    float dy = s_posn[a1*3+1] - s_posnb[k*16 + a2*3+1];
    float dz = s_posn[a1*3+2] - s_posnb[k*16 + a2*3+2];
    float d2 = dx*dx + dy*dy + dz*dz;
    s_xall[48 + idx] = sqrtf(fmaxf(d2, 1e-12f)) * INV_STEP;
  }
  __syncthreads();

  // ---------------- GEMM1 over 3x128 + 1x96 K-stages (relpos NOT in GEMM) ----
  f32x4 acc1[3][2] = {};

  #pragma unroll 1
  for (int st = 0; st < 3; ++st) {
    stage_bins(sF, s_xall, st*8, 384, t);
    __syncthreads();
    #pragma unroll
    for (int kc = 0; kc < 4; ++kc) {
      const unsigned short* ab = sF + FOCT(kc*4 + quad, ln15);
      bf16x8 a0 = *(const bf16x8*)(ab);
      bf16x8 a1 = *(const bf16x8*)(ab + 128);
      bf16x8 a2 = *(const bf16x8*)(ab + 256);
      const unsigned short* bb = g_wcat + (((st*4+kc)*4 + quad)*128 + 32*wv + ln15)*8;
      bf16x8 b0 = *(const bf16x8*)(bb);
      bf16x8 b1v= *(const bf16x8*)(bb + 128);
      MFMA6(a0,a1,a2,b0,b1v,acc1)
    }
    __syncthreads();
  }

  // stage 3: local k 0..31 dist c23,c24 | 32..46 dir | 47..61 vec | 62..70 rot |
  //          71 zero (folded into rot loop) | 72..95 zero-fill (octs 9..11).
  // All writers disjoint -> single barrier for the whole stage.
  for (int i = t; i < 147; i += 256) ((uint4*)sF)[441 + i] = make_uint4(0,0,0,0);
  stage_bins(sF, s_xall, 24, 96, t);
  for (int idx = t; idx < 240; idx += 256) {   // dir (l=32..46) + vec (l=47..61)
    int k = idx / 5, a = idx - 5*k;
    float rx = s_posnb[k*16 + a*3+0] - s_posn[3];
    float ry = s_posnb[k*16 + a*3+1] - s_posn[4];
    float rz = s_posnb[k*16 + a*3+2] - s_posn[5];
    float l0 = s_Rn[0]*rx + s_Rn[3]*ry + s_Rn[6]*rz;
    float l1 = s_Rn[1]*rx + s_Rn[4]*ry + s_Rn[7]*rz;
    float l2 = s_Rn[2]*rx + s_Rn[5]*ry + s_Rn[8]*rz;
    float inv = __builtin_amdgcn_rsqf(fmaxf(l0*l0 + l1*l1 + l2*l2, 1e-6f));
    int lv = 47 + a*3, ld = 32 + a*3;
    sF[FOCT(lv>>3,k) + (lv&7)] = f2bf(l0);
    lv++; sF[FOCT(lv>>3,k) + (lv&7)] = f2bf(l1);
    lv++; sF[FOCT(lv>>3,k) + (lv&7)] = f2bf(l2);
    sF[FOCT(ld>>3,k) + (ld&7)] = f2bf(l0*inv);
    ld++; sF[FOCT(ld>>3,k) + (ld&7)] = f2bf(l1*inv);
    ld++; sF[FOCT(ld>>3,k) + (ld&7)] = f2bf(l2*inv);
  }
  for (int idx = t; idx < 480; idx += 256) {   // rot (l=62..70) + zero (l=71)
    int k = idx / 10, il = idx - 10*k;
    float v = 0.0f;
    if (il < 9) {
      int i2 = il / 3, l2c = il - 3*i2;
      v = s_Rn[0+i2]*s_Rnb[k*12 + 0+l2c]
        + s_Rn[3+i2]*s_Rnb[k*12 + 3+l2c]
        + s_Rn[6+i2]*s_Rnb[k*12 + 6+l2c];
    }
    int l = 62 + il;
    sF[FOCT(l>>3,k) + (l&7)] = f2bf(v);
  }
  __syncthreads();
  #pragma unroll
  for (int kc = 0; kc < 3; ++kc) {
    const unsigned short* ab = sF + FOCT(kc*4 + quad, ln15);
    bf16x8 a0 = *(const bf16x8*)(ab);
    bf16x8 a1 = *(const bf16x8*)(ab + 128);
    bf16x8 a2 = *(const bf16x8*)(ab + 256);
    const unsigned short* bb = g_wcat + (((12+kc)*4 + quad)*128 + 32*wv + ln15)*8;
    bf16x8 b0 = *(const bf16x8*)(bb);
    bf16x8 b1v= *(const bf16x8*)(bb + 128);
    MFMA6(a0,a1,a2,b0,b1v,acc1)
  }

  // ---------------- relpos: exact f32 table add (replaces one-hot GEMM) ----
  {
    int c0 = 32*wv + ln15;
    #pragma unroll
    for (int mt = 0; mt < 3; ++mt)
      #pragma unroll
      for (int r = 0; r < 4; ++r) {
        int row = mt*16 + quad*4 + r;
        const float* wr = W_relpos + s_cls[row]*128 + c0;
        acc1[mt][0][r] += wr[0];
        acc1[mt][1][r] += wr[16];
      }
  }

  // ---------------- LayerNorm in registers ----------------
  #pragma unroll
  for (int mt = 0; mt < 3; ++mt)
    #pragma unroll
    for (int r = 0; r < 4; ++r) {
      float a0v = acc1[mt][0][r], a1v = acc1[mt][1][r];
      float sv = a0v + a1v;
      float qv = a0v*a0v + a1v*a1v;
      #pragma unroll
      for (int msk = 1; msk < 16; msk <<= 1) {
        sv += __shfl_xor(sv, msk);
        qv += __shfl_xor(qv, msk);
      }
      if (ln15 == 0) s_part[wv*48 + mt*16 + quad*4 + r] = make_float2(sv, qv);
    }
  __syncthreads();
  if (t < 48) {
    float S = 0.0f, Q = 0.0f;
    #pragma unroll
    for (int w = 0; w < 4; ++w) { float2 p = s_part[w*48 + t]; S += p.x; Q += p.y; }
    float mu = S * (1.0f/128.0f);
    float var = Q * (1.0f/128.0f) - mu*mu;
    s_stats[t] = make_float2(mu, __builtin_amdgcn_rsqf(var + 1e-5f));
  }
  __syncthreads();
  {
    int c0 = 32*wv + ln15;
    float gg0 = ln_scale[c0],  gg1 = ln_scale[c0+16];
    float oo0 = ln_offset[c0], oo1 = ln_offset[c0+16];
    int kp = 32*wv + 2*ln15;                 // sigma-permuted K position (even)
    int oct = kp >> 3, slot = kp & 7;
    #pragma unroll
    for (int mt = 0; mt < 3; ++mt)
      #pragma unroll
      for (int r = 0; r < 4; ++r) {
        int row = mt*16 + quad*4 + r;
        float2 stt = s_stats[row];
        float v0 = (acc1[mt][0][r] - stt.x)*stt.y*gg0 + oo0;
        float v1 = (acc1[mt][1][r] - stt.x)*stt.y*gg1 + oo1;
        *(unsigned int*)(sPair + FOCT(oct,row) + slot) = pk2(v0, v1);
      }
  }
  __syncthreads();

  // ---------------- MLP: two hidden halves of 128 ----------------
  f32x4 acc3[3][2] = {};
  #pragma unroll 1
  for (int half = 0; half < 2; ++half) {
    f32x4 acc2[3][2] = {};
    #pragma unroll
    for (int kc = 0; kc < 4; ++kc) {
      const unsigned short* ab = sPair + FOCT(kc*4 + quad, ln15);
      bf16x8 a0 = *(const bf16x8*)(ab);
      bf16x8 a1 = *(const bf16x8*)(ab + 128);
      bf16x8 a2 = *(const bf16x8*)(ab + 256);
      const unsigned short* bb = g_w1 + ((kc*4 + quad)*256 + half*128 + 32*wv + ln15)*8;
      bf16x8 b0 = *(const bf16x8*)(bb);
      bf16x8 b1v= *(const bf16x8*)(bb + 128);
      MFMA6(a0,a1,a2,b0,b1v,acc2)
    }
    __syncthreads();   // previous readers of sF are done
    {
      int hc = half*128 + 32*wv + ln15;
      float bb0 = b1[hc], bb1 = b1[hc+16];
      int kp = 32*wv + 2*ln15;
      int oct = kp >> 3, slot = kp & 7;
      #pragma unroll
      for (int mt = 0; mt < 3; ++mt)
        #pragma unroll
        for (int r = 0; r < 4; ++r) {
          int row = mt*16 + quad*4 + r;
          float h0 = gelu_f(acc2[mt][0][r] + bb0);
          float h1 = gelu_f(acc2[mt][1][r] + bb1);
          *(unsigned int*)(sF + FOCT(oct,row) + slot) = pk2(h0, h1);
        }
    }
    __syncthreads();
    #pragma unroll
    for (int kc = 0; kc < 4; ++kc) {
      const unsigned short* ab = sF + FOCT(kc*4 + quad, ln15);
      bf16x8 a0 = *(const bf16x8*)(ab);
      bf16x8 a1 = *(const bf16x8*)(ab + 128);
      bf16x8 a2 = *(const bf16x8*)(ab + 256);
      const unsigned short* bb = g_w2 + (((half*4 + kc)*4 + quad)*128 + 32*wv + ln15)*8;
      bf16x8 b0 = *(const bf16x8*)(bb);
      bf16x8 b1v= *(const bf16x8*)(bb + 128);
      MFMA6(a0,a1,a2,b0,b1v,acc3)
    }
  }

  // ---------------- epilogue: out = acc3 + b2 ----------------
  {
    int c0 = 32*wv + ln15;
    float bo0 = b2[c0], bo1 = b2[c0+16];
    #pragma unroll
    for (int mt = 0; mt < 3; ++mt)
      #pragma unroll
      for (int r = 0; r < 4; ++r) {
        int row = mt*16 + quad*4 + r;
        out[(n*KNB + row)*PCH + c0]      = acc3[mt][0][r] + bo0;
        out[(n*KNB + row)*PCH + c0 + 16] = acc3[mt][1][r] + bo1;
      }
  }
}

extern "C" void kernel_launch(void* const* d_in, const int* in_sizes, int n_in,
                              void* d_out, int out_size, void* d_ws, size_t ws_size,
                              hipStream_t stream) {
  const float* pos       = (const float*)d_in[0];
  const float* dmap      = (const float*)d_in[1];
  const float* mask      = (const float*)d_in[2];
  const float* W_relpos  = (const float*)d_in[3];
  const float* W_dmap    = (const float*)d_in[4];
  const float* W_dist    = (const float*)d_in[5];
  const float* W_dir     = (const float*)d_in[6];
  const float* W_rot     = (const float*)d_in[7];
  const float* W_vec     = (const float*)d_in[8];
  const float* ln_scale  = (const float*)d_in[9];
  const float* ln_offset = (const float*)d_in[10];
  const float* W1        = (const float*)d_in[11];
  const float* b1        = (const float*)d_in[12];
  const float* W2        = (const float*)d_in[13];
  const float* b2        = (const float*)d_in[14];
  const int* neighbours  = (const int*)d_in[15];
  const int* resi        = (const int*)d_in[16];
  const int* chain       = (const int*)d_in[17];
  const int* batch       = (const int*)d_in[18];
  float* out = (float*)d_out;

  hipLaunchKernelGGL(prep_weights, dim3(62), dim3(256), 0, stream,
                     W_dmap, W_dist, W_dir, W_rot, W_vec, W1, W2);
  hipLaunchKernelGGL(fused_struct_kernel, dim3(N_RES), dim3(256), 0, stream,
                     pos, dmap, mask, W_relpos, ln_scale, ln_offset, b1, b2,
                     neighbours, resi, chain, batch, out);
}